// Round 7
// baseline (148.065 us; speedup 1.0000x reference)
//
#include <hip/hip_runtime.h>
#include <hip/hip_bf16.h>
#include <math.h>

#define BATCH 4
#define NQ 8192
#define KNB 8
#define K1 9            // keep 9 per partition: self filtered at merge
#define CAP 34          // u16 survivor entries per thread (stride 17 dwords: conflict-free)
#define THSAMP 256      // theta subsample size per theta-partition
#define SPART 2         // theta partitions (disjoint subsamples, min-merged)
#define IDXMASK 8191u
#define KEYMASK 0xFFFFE000u  // keep sign+exp+10 mantissa bits, low 13 bits hold index
#define EPS_S 1e-3f     // gate slack >> fp32 error of the 3-fma score form

// branchless sorted insert into ascending nk[0..K1-1]
#define CHAIN9(KEY) { unsigned kk = (KEY); \
  _Pragma("unroll") \
  for (int j = 0; j < K1; ++j) { \
    unsigned lo = min(kk, nk[j]); unsigned hi = max(kk, nk[j]); \
    nk[j] = lo; kk = hi; } }

// drain survivors: recompute EXACT keys (R1-identical arithmetic) from global
// coords (rare, divergent, L2-hit), chain them, tighten the score gate
#define DRAIN() { \
  for (int i = 0; i < cnt; ++i) { \
    int j = sbuf[base + i]; \
    float dx = qx - px[j], dy = qy - py[j], dz = qz - pz[j]; \
    float d = dx*dx + dy*dy + dz*dz; \
    unsigned key = (__float_as_uint(d) & KEYMASK) | (unsigned)j; \
    if (key < nk[K1-1]) CHAIN9(key); \
  } \
  cnt = 0; \
  if (nk[K1-1] != 0xFFFFFFFFu) { \
    float td = __uint_as_float(nk[K1-1] | 0x1FFFu); \
    thetaS = fminf(thetaS, 0.5f*(td - qq) + EPS_S); \
  } }

// survivor push: exec-masked (rare) store of global u16 candidate index
#define GPROC(SS, GIDX) { \
  if ((SS) <= thetaS) { sbuf[base + cnt] = (unsigned short)(GIDX); cnt++; } }

// 4 scores from one float4 quad (X,Y,Z,H are wave-uniform -> SGPR operands)
#define SCORE4(S0,S1,S2,S3, X,Y,Z,H) \
  float S0 = fmaf(nqx, X.x, fmaf(nqy, Y.x, fmaf(nqz, Z.x, H.x))); \
  float S1 = fmaf(nqx, X.y, fmaf(nqy, Y.y, fmaf(nqz, Z.y, H.y))); \
  float S2 = fmaf(nqx, X.z, fmaf(nqy, Y.z, fmaf(nqz, Z.z, H.z))); \
  float S3 = fmaf(nqx, X.w, fmaf(nqy, Y.w, fmaf(nqz, Z.w, H.w)));

// ---- theta bound (9th-of-256-subsample, x2 disjoint) + h = 0.5*||c||^2 ----
__global__ __launch_bounds__(256) void theta_kernel(
    const float* __restrict__ pc, unsigned* __restrict__ thetaOut,
    float* __restrict__ hOut)
{
  __shared__ float swx[THSAMP], swy[THSAMP], swz[THSAMP];
  const int b = blockIdx.y, p = blockIdx.z;
  const int q = blockIdx.x * 256 + threadIdx.x;
  const float* __restrict__ px = pc + (size_t)b * 3 * NQ;
  const float* __restrict__ py = px + NQ;
  const float* __restrict__ pz = px + 2 * NQ;
  const int tid = threadIdx.x;
  const int si = tid * (NQ / THSAMP) + p * (NQ / THSAMP / SPART);
  swx[tid] = px[si]; swy[tid] = py[si]; swz[tid] = pz[si];
  __syncthreads();
  const float qx = px[q], qy = py[q], qz = pz[q];
  if (p == 0) hOut[b * NQ + q] = 0.5f * (qx*qx + qy*qy + qz*qz);
  unsigned nk[K1];
#pragma unroll
  for (int j = 0; j < K1; ++j) nk[j] = 0xFFFFFFFFu;
  for (int i = 0; i < THSAMP; ++i) {
    float dx = qx - swx[i], dy = qy - swy[i], dz = qz - swz[i];
    float d = dx * dx + dy * dy + dz * dz;
    CHAIN9(__float_as_uint(d));
  }
  thetaOut[(size_t)(b * NQ + q) * SPART + p] = nk[K1 - 1] | 0x1FFFu;
}

__global__ __launch_bounds__(256) void knn_kernel(
    const float* __restrict__ pc, const float* __restrict__ hB,
    const unsigned* __restrict__ thetaIn, unsigned* __restrict__ wsK,
    int P, int cpp)
{
  __shared__ unsigned short sbuf[256 * CAP];
  const int b = blockIdx.y;
  const int p = blockIdx.z;
  const int q = blockIdx.x * 256 + threadIdx.x;
  const float* __restrict__ px = pc + (size_t)b * 3 * NQ;
  const float* __restrict__ py = px + NQ;
  const float* __restrict__ pz = px + 2 * NQ;
  const float* __restrict__ ph = hB + (size_t)b * NQ;
  const float4* __restrict__ px4 = (const float4*)px;
  const float4* __restrict__ py4 = (const float4*)py;
  const float4* __restrict__ pz4 = (const float4*)pz;
  const float4* __restrict__ ph4 = (const float4*)ph;
  const float qx = px[q], qy = py[q], qz = pz[q];
  const float nqx = -qx, nqy = -qy, nqz = -qz;
  const float qq = qx*qx + qy*qy + qz*qz;

  uint2 th = ((const uint2*)thetaIn)[b * NQ + q];
  float thetaS = 0.5f * (__uint_as_float(min(th.x, th.y)) - qq) + EPS_S;

  unsigned nk[K1];
#pragma unroll
  for (int j = 0; j < K1; ++j) nk[j] = 0xFFFFFFFFu;

  const unsigned base = (unsigned)threadIdx.x * CAP;
  int cnt = 0;
  const int c0 = p * cpp;

  // scan: candidates via wave-uniform loads (scalar path), no LDS staging
  for (int t = 0; t < cpp; t += 8) {
    if (__any(cnt >= CAP - 8)) { DRAIN(); }
    const int ti = (c0 + t) >> 2;
    const float4 X0 = px4[ti], X1 = px4[ti + 1];
    const float4 Y0 = py4[ti], Y1 = py4[ti + 1];
    const float4 Z0 = pz4[ti], Z1 = pz4[ti + 1];
    const float4 H0 = ph4[ti], H1 = ph4[ti + 1];
    SCORE4(s0, s1, s2, s3, X0, Y0, Z0, H0);
    SCORE4(s4, s5, s6, s7, X1, Y1, Z1, H1);
    const int g = c0 + t;
    GPROC(s0, g + 0); GPROC(s1, g + 1); GPROC(s2, g + 2); GPROC(s3, g + 3);
    GPROC(s4, g + 4); GPROC(s5, g + 5); GPROC(s6, g + 6); GPROC(s7, g + 7);
  }
  DRAIN();

  // transposed layout: [(b,p,j)][q] -> coalesced store here, coalesced read in loss
#pragma unroll
  for (int j = 0; j < K1; ++j)
    wsK[((size_t)(b * P + p) * K1 + j) * NQ + q] = nk[j];
}

__global__ __launch_bounds__(256) void loss_kernel(
    const float* __restrict__ pc, const float* __restrict__ pf,
    const unsigned* __restrict__ wsK, float* __restrict__ acc, int P)
{
  const int b = blockIdx.y;
  const int q = blockIdx.x * 256 + threadIdx.x;
  const float* __restrict__ px = pc + (size_t)b * 3 * NQ;
  const float* __restrict__ py = px + NQ;
  const float* __restrict__ pz = px + 2 * NQ;
  const float* __restrict__ fx = pf + (size_t)b * 3 * NQ;
  const float* __restrict__ fy = fx + NQ;
  const float* __restrict__ fz = fx + 2 * NQ;

  unsigned nk[KNB];
#pragma unroll
  for (int j = 0; j < KNB; ++j) nk[j] = 0xFFFFFFFFu;

  const int total = P * K1;
  for (int m = 0; m < total; ++m) {
    unsigned key = wsK[((size_t)b * P * K1 + m) * NQ + q];  // coalesced
    if ((key & IDXMASK) == (unsigned)q) continue;  // drop self
    if (key < nk[KNB - 1]) {
      unsigned kk = key;
#pragma unroll
      for (int j = 0; j < KNB; ++j) {
        unsigned lo = min(kk, nk[j]); unsigned hi = max(kk, nk[j]);
        nk[j] = lo; kk = hi;
      }
    }
  }

  const float qx = px[q], qy = py[q], qz = pz[q];
  const float fqx = fx[q], fqy = fy[q], fqz = fz[q];
  float ssum = 0.f, sdsum = 0.f;
#pragma unroll
  for (int j = 0; j < KNB; ++j) {
    int i = (int)(nk[j] & IDXMASK);
    float dx = qx - px[i], dy = qy - py[i], dz = qz - pz[i];
    float d = dx * dx + dy * dy + dz * dz;
    float e = expf(expf(-2.0f * d));  // exp(exp(-d/alpha)), alpha=0.5
    float gx = fx[i] - fqx, gy = fy[i] - fqy, gz = fz[i] - fqz;
    float diff = sqrtf(gx * gx + gy * gy + gz * gz);
    ssum += e; sdsum += e * diff;
  }

  for (int off = 32; off > 0; off >>= 1) {
    ssum += __shfl_down(ssum, off);
    sdsum += __shfl_down(sdsum, off);
  }
  __shared__ float r[8];
  const int lane = threadIdx.x & 63, wid = threadIdx.x >> 6;
  if (lane == 0) { r[wid * 2] = ssum; r[wid * 2 + 1] = sdsum; }
  __syncthreads();
  if (threadIdx.x == 0) {
    float s0 = r[0] + r[2] + r[4] + r[6];
    float s1 = r[1] + r[3] + r[5] + r[7];
    atomicAdd(&acc[b * 2 + 0], s0);
    atomicAdd(&acc[b * 2 + 1], s1);
  }
}

__global__ void final_kernel(const float* __restrict__ acc, float* __restrict__ out)
{
  if (threadIdx.x == 0) {
    float s = 0.f;
    for (int b = 0; b < BATCH; ++b) s += acc[b * 2 + 1] / acc[b * 2];
    out[0] = s * (1.0f / BATCH);
  }
}

extern "C" void kernel_launch(void* const* d_in, const int* in_sizes, int n_in,
                              void* d_out, int out_size, void* d_ws, size_t ws_size,
                              hipStream_t stream) {
  const float* pc = (const float*)d_in[0];   // pc1:      (4,3,8192) f32
  const float* pf = (const float*)d_in[1];   // pred_flow:(4,3,8192) f32
  float* out = (float*)d_out;                // scalar f32
  float* acc = (float*)d_ws;                 // 8 floats: per-batch {sum_e, sum_e_diff}
  const size_t thetaBytes = (size_t)BATCH * NQ * SPART * sizeof(unsigned);  // 256 KB
  const size_t hBytes = (size_t)BATCH * NQ * sizeof(float);                 // 128 KB
  unsigned* thetaBuf = (unsigned*)((char*)d_ws + 256);
  float* hBuf = (float*)((char*)d_ws + 256 + thetaBytes);
  unsigned* wsK = (unsigned*)((char*)d_ws + 256 + thetaBytes + hBytes);

  const size_t fixed = 256 + thetaBytes + hBytes;
  const size_t needP16 = fixed + (size_t)BATCH * NQ * 16 * K1 * sizeof(unsigned);
  const size_t needP8  = fixed + (size_t)BATCH * NQ * 8  * K1 * sizeof(unsigned);
  const size_t needP4  = fixed + (size_t)BATCH * NQ * 4  * K1 * sizeof(unsigned);
  const int P = (ws_size >= needP16) ? 16 : (ws_size >= needP8) ? 8
              : (ws_size >= needP4) ? 4 : 1;
  const int cpp = NQ / P;

  hipMemsetAsync(d_ws, 0, 256, stream);  // zero accumulators

  dim3 g0(NQ / 256, BATCH, SPART);
  theta_kernel<<<g0, 256, 0, stream>>>(pc, thetaBuf, hBuf);

  dim3 g1(NQ / 256, BATCH, P);
  knn_kernel<<<g1, 256, 0, stream>>>(pc, hBuf, thetaBuf, wsK, P, cpp);

  dim3 g2(NQ / 256, BATCH);
  loss_kernel<<<g2, 256, 0, stream>>>(pc, pf, wsK, acc, P);

  final_kernel<<<1, 64, 0, stream>>>(acc, out);
}

// Round 9
// 142.784 us; speedup vs baseline: 1.0370x; 1.0370x over previous
//
#include <hip/hip_runtime.h>
#include <hip/hip_bf16.h>
#include <math.h>

#define BATCH 4
#define NQ 8192
#define KNB 8
#define K1 9            // keep 9 per partition: self filtered at merge
#define CAP 34          // u16 survivor entries per thread (stride 17 dwords: conflict-free)
#define THSAMP 256      // theta subsample size per theta-partition
#define SPART 2         // theta partitions (disjoint subsamples, min-merged)
#define IDXMASK 8191u
#define KEYMASK 0xFFFFE000u  // keep sign+exp+10 mantissa bits, low 13 bits hold index
#define EPS_S 1e-3f     // gate slack >> fp32 error of the 3-fma score form

// branchless sorted insert into ascending nk[0..K1-1] (9-deep, knn side)
#define CHAIN9(KEY) { unsigned kk = (KEY); \
  _Pragma("unroll") \
  for (int j = 0; j < K1; ++j) { \
    unsigned lo = min(kk, nk[j]); unsigned hi = max(kk, nk[j]); \
    nk[j] = lo; kk = hi; } }

// branchless sorted insert into ascending nk[0..KNB-1] (8-deep, loss side)
#define CHAIN8(KEY) { unsigned kk = (KEY); \
  _Pragma("unroll") \
  for (int j = 0; j < KNB; ++j) { \
    unsigned lo = min(kk, nk[j]); unsigned hi = max(kk, nk[j]); \
    nk[j] = lo; kk = hi; } }

// drain survivors: recompute EXACT keys (R1-identical arithmetic) from global
// coords (rare, divergent, L2-hit), chain them, tighten the score gate
#define DRAIN() { \
  for (int i = 0; i < cnt; ++i) { \
    int j = sbuf[base + i]; \
    float dx = qx - px[j], dy = qy - py[j], dz = qz - pz[j]; \
    float d = dx*dx + dy*dy + dz*dz; \
    unsigned key = (__float_as_uint(d) & KEYMASK) | (unsigned)j; \
    if (key < nk[K1-1]) CHAIN9(key); \
  } \
  cnt = 0; \
  if (nk[K1-1] != 0xFFFFFFFFu) { \
    float td = __uint_as_float(nk[K1-1] | 0x1FFFu); \
    thetaS = fminf(thetaS, 0.5f*(td - qq) + EPS_S); \
  } }

// survivor push: exec-masked (rare) store of global u16 candidate index
#define GPROC(SS, GIDX) { \
  if ((SS) <= thetaS) { sbuf[base + cnt] = (unsigned short)(GIDX); cnt++; } }

// 4 scores from one float4 quad (X,Y,Z,H are wave-uniform -> SGPR operands)
#define SCORE4(S0,S1,S2,S3, X,Y,Z,H) \
  float S0 = fmaf(nqx, X.x, fmaf(nqy, Y.x, fmaf(nqz, Z.x, H.x))); \
  float S1 = fmaf(nqx, X.y, fmaf(nqy, Y.y, fmaf(nqz, Z.y, H.y))); \
  float S2 = fmaf(nqx, X.z, fmaf(nqy, Y.z, fmaf(nqz, Z.z, H.z))); \
  float S3 = fmaf(nqx, X.w, fmaf(nqy, Y.w, fmaf(nqz, Z.w, H.w)));

// ---- theta bound (9th-of-256-subsample, x2 disjoint) + h = 0.5*||c||^2 ----
__global__ __launch_bounds__(256) void theta_kernel(
    const float* __restrict__ pc, unsigned* __restrict__ thetaOut,
    float* __restrict__ hOut)
{
  __shared__ float swx[THSAMP], swy[THSAMP], swz[THSAMP];
  const int b = blockIdx.y, p = blockIdx.z;
  const int q = blockIdx.x * 256 + threadIdx.x;
  const float* __restrict__ px = pc + (size_t)b * 3 * NQ;
  const float* __restrict__ py = px + NQ;
  const float* __restrict__ pz = px + 2 * NQ;
  const int tid = threadIdx.x;
  const int si = tid * (NQ / THSAMP) + p * (NQ / THSAMP / SPART);
  swx[tid] = px[si]; swy[tid] = py[si]; swz[tid] = pz[si];
  __syncthreads();
  const float qx = px[q], qy = py[q], qz = pz[q];
  if (p == 0) hOut[b * NQ + q] = 0.5f * (qx*qx + qy*qy + qz*qz);
  unsigned nk[K1];
#pragma unroll
  for (int j = 0; j < K1; ++j) nk[j] = 0xFFFFFFFFu;
  for (int i = 0; i < THSAMP; ++i) {
    float dx = qx - swx[i], dy = qy - swy[i], dz = qz - swz[i];
    float d = dx * dx + dy * dy + dz * dz;
    CHAIN9(__float_as_uint(d));
  }
  thetaOut[(size_t)(b * NQ + q) * SPART + p] = nk[K1 - 1] | 0x1FFFu;
}

__global__ __launch_bounds__(256) void knn_kernel(
    const float* __restrict__ pc, const float* __restrict__ hB,
    const unsigned* __restrict__ thetaIn, unsigned* __restrict__ wsK,
    int P, int cpp)
{
  __shared__ unsigned short sbuf[256 * CAP];
  const int b = blockIdx.y;
  const int p = blockIdx.z;
  const int q = blockIdx.x * 256 + threadIdx.x;
  const float* __restrict__ px = pc + (size_t)b * 3 * NQ;
  const float* __restrict__ py = px + NQ;
  const float* __restrict__ pz = px + 2 * NQ;
  const float* __restrict__ ph = hB + (size_t)b * NQ;
  const float4* __restrict__ px4 = (const float4*)px;
  const float4* __restrict__ py4 = (const float4*)py;
  const float4* __restrict__ pz4 = (const float4*)pz;
  const float4* __restrict__ ph4 = (const float4*)ph;
  const float qx = px[q], qy = py[q], qz = pz[q];
  const float nqx = -qx, nqy = -qy, nqz = -qz;
  const float qq = qx*qx + qy*qy + qz*qz;

  uint2 th = ((const uint2*)thetaIn)[b * NQ + q];
  float thetaS = 0.5f * (__uint_as_float(min(th.x, th.y)) - qq) + EPS_S;

  unsigned nk[K1];
#pragma unroll
  for (int j = 0; j < K1; ++j) nk[j] = 0xFFFFFFFFu;

  const unsigned base = (unsigned)threadIdx.x * CAP;
  int cnt = 0;
  const int c0 = p * cpp;

  // scan: candidates via wave-uniform loads (scalar path), 16 per burst
  for (int t = 0; t < cpp; t += 16) {
    if (__any(cnt >= CAP - 16)) { DRAIN(); }
    const int ti = (c0 + t) >> 2;
    const float4 X0 = px4[ti],     X1 = px4[ti + 1], X2 = px4[ti + 2], X3 = px4[ti + 3];
    const float4 Y0 = py4[ti],     Y1 = py4[ti + 1], Y2 = py4[ti + 2], Y3 = py4[ti + 3];
    const float4 Z0 = pz4[ti],     Z1 = pz4[ti + 1], Z2 = pz4[ti + 2], Z3 = pz4[ti + 3];
    const float4 H0 = ph4[ti],     H1 = ph4[ti + 1], H2 = ph4[ti + 2], H3 = ph4[ti + 3];
    SCORE4(s0, s1, s2, s3, X0, Y0, Z0, H0);
    SCORE4(s4, s5, s6, s7, X1, Y1, Z1, H1);
    SCORE4(s8, s9, sa, sb, X2, Y2, Z2, H2);
    SCORE4(sc, sd, se, sf, X3, Y3, Z3, H3);
    const int g = c0 + t;
    GPROC(s0, g + 0);  GPROC(s1, g + 1);  GPROC(s2, g + 2);  GPROC(s3, g + 3);
    GPROC(s4, g + 4);  GPROC(s5, g + 5);  GPROC(s6, g + 6);  GPROC(s7, g + 7);
    GPROC(s8, g + 8);  GPROC(s9, g + 9);  GPROC(sa, g + 10); GPROC(sb, g + 11);
    GPROC(sc, g + 12); GPROC(sd, g + 13); GPROC(se, g + 14); GPROC(sf, g + 15);
  }
  DRAIN();

  // transposed layout: [(b,p,j)][q] -> coalesced store here, coalesced read in loss
#pragma unroll
  for (int j = 0; j < K1; ++j)
    wsK[((size_t)(b * P + p) * K1 + j) * NQ + q] = nk[j];
}

// loss + final fused: one wave per 64 queries; last block computes the scalar
__global__ __launch_bounds__(64) void loss_kernel(
    const float* __restrict__ pc, const float* __restrict__ pf,
    const unsigned* __restrict__ wsK, float* __restrict__ acc,
    unsigned* __restrict__ doneCtr, float* __restrict__ out,
    int P, int nBlocks)
{
  const int b = blockIdx.y;
  const int q = blockIdx.x * 64 + threadIdx.x;
  const float* __restrict__ px = pc + (size_t)b * 3 * NQ;
  const float* __restrict__ py = px + NQ;
  const float* __restrict__ pz = px + 2 * NQ;
  const float* __restrict__ fx = pf + (size_t)b * 3 * NQ;
  const float* __restrict__ fy = fx + NQ;
  const float* __restrict__ fz = fx + 2 * NQ;

  unsigned nk[KNB];
#pragma unroll
  for (int j = 0; j < KNB; ++j) nk[j] = 0xFFFFFFFFu;

  const int total = P * K1;
  const size_t stride0 = (size_t)b * P * K1;
  // chunked merge: 9 coalesced loads in flight, then process (8-deep chain!)
  for (int m0 = 0; m0 < total; m0 += K1) {
    unsigned kb[K1];
#pragma unroll
    for (int u = 0; u < K1; ++u)
      kb[u] = wsK[(stride0 + m0 + u) * NQ + q];
#pragma unroll
    for (int u = 0; u < K1; ++u) {
      unsigned key = kb[u];
      if ((key & IDXMASK) == (unsigned)q) continue;  // drop self
      if (key < nk[KNB - 1]) CHAIN8(key);
    }
  }

  const float qx = px[q], qy = py[q], qz = pz[q];
  const float fqx = fx[q], fqy = fy[q], fqz = fz[q];
  float ssum = 0.f, sdsum = 0.f;
#pragma unroll
  for (int j = 0; j < KNB; ++j) {
    int i = (int)(nk[j] & IDXMASK);
    float dx = qx - px[i], dy = qy - py[i], dz = qz - pz[i];
    float d = dx * dx + dy * dy + dz * dz;
    float e = expf(expf(-2.0f * d));  // exp(exp(-d/alpha)), alpha=0.5
    float gx = fx[i] - fqx, gy = fy[i] - fqy, gz = fz[i] - fqz;
    float diff = sqrtf(gx * gx + gy * gy + gz * gz);
    ssum += e; sdsum += e * diff;
  }

  for (int off = 32; off > 0; off >>= 1) {
    ssum += __shfl_down(ssum, off);
    sdsum += __shfl_down(sdsum, off);
  }
  if (threadIdx.x == 0) {
    atomicAdd(&acc[b * 2 + 0], ssum);
    atomicAdd(&acc[b * 2 + 1], sdsum);
    __threadfence();
    unsigned done = atomicAdd(doneCtr, 1u);
    if (done == (unsigned)(nBlocks - 1)) {
      float s = 0.f;
      for (int bb = 0; bb < BATCH; ++bb) {
        float se = atomicAdd(&acc[bb * 2 + 0], 0.f);   // coherent read
        float sd = atomicAdd(&acc[bb * 2 + 1], 0.f);
        s += sd / se;
      }
      out[0] = s * (1.0f / BATCH);
    }
  }
}

extern "C" void kernel_launch(void* const* d_in, const int* in_sizes, int n_in,
                              void* d_out, int out_size, void* d_ws, size_t ws_size,
                              hipStream_t stream) {
  const float* pc = (const float*)d_in[0];   // pc1:      (4,3,8192) f32
  const float* pf = (const float*)d_in[1];   // pred_flow:(4,3,8192) f32
  float* out = (float*)d_out;                // scalar f32
  float* acc = (float*)d_ws;                 // 8 floats: per-batch {sum_e, sum_e_diff}
  unsigned* doneCtr = (unsigned*)((char*)d_ws + 64);
  const size_t thetaBytes = (size_t)BATCH * NQ * SPART * sizeof(unsigned);  // 256 KB
  const size_t hBytes = (size_t)BATCH * NQ * sizeof(float);                 // 128 KB
  unsigned* thetaBuf = (unsigned*)((char*)d_ws + 256);
  float* hBuf = (float*)((char*)d_ws + 256 + thetaBytes);
  unsigned* wsK = (unsigned*)((char*)d_ws + 256 + thetaBytes + hBytes);

  const size_t fixed = 256 + thetaBytes + hBytes;
  const size_t needP16 = fixed + (size_t)BATCH * NQ * 16 * K1 * sizeof(unsigned);
  const size_t needP8  = fixed + (size_t)BATCH * NQ * 8  * K1 * sizeof(unsigned);
  const size_t needP4  = fixed + (size_t)BATCH * NQ * 4  * K1 * sizeof(unsigned);
  const int P = (ws_size >= needP16) ? 16 : (ws_size >= needP8) ? 8
              : (ws_size >= needP4) ? 4 : 1;
  const int cpp = NQ / P;

  hipMemsetAsync(d_ws, 0, 256, stream);  // zero accumulators + done counter

  dim3 g0(NQ / 256, BATCH, SPART);
  theta_kernel<<<g0, 256, 0, stream>>>(pc, thetaBuf, hBuf);

  dim3 g1(NQ / 256, BATCH, P);
  knn_kernel<<<g1, 256, 0, stream>>>(pc, hBuf, thetaBuf, wsK, P, cpp);

  dim3 g2(NQ / 64, BATCH);
  const int nBlocks = (NQ / 64) * BATCH;
  loss_kernel<<<g2, 64, 0, stream>>>(pc, pf, wsK, acc, doneCtr, out, P, nBlocks);
}